// Round 12
// baseline (1979.731 us; speedup 1.0000x reference)
//
#include <hip/hip_runtime.h>
#include <hip/hip_bf16.h>

typedef __hip_bfloat16 bf16;
typedef __attribute__((ext_vector_type(8))) short bf16x8;
typedef __attribute__((ext_vector_type(4))) float f32x4;

#define NPTS  32768
#define NPB   4096
#define NPAIR (NPTS*16)
#define IMASK 32767
#define EPSB  1e-5f

// packed fp32 param-block offsets (floats)
#define O_WQ  0
#define O_BQ  4096
#define O_WK  4160
#define O_BK  8256
#define O_WV  8320
#define O_BV  12416
#define O_WP1 12480
#define O_BP1 12489
#define O_GP  12492
#define O_BTP 12495
#define O_WP2 12498
#define O_BP2 12690
#define O_G1  12754
#define O_BT1 12818
#define O_WW1 12882
#define O_BW1 13394
#define O_G2  13402
#define O_BT2 13410
#define O_WW2 13418
#define O_BW2 13482
#define NPRM  13490

__device__ __forceinline__ float b2f(bf16 v){ return __bfloat162float(v); }
__device__ __forceinline__ float u16f(unsigned short u){ return __uint_as_float(((unsigned)u)<<16); }
__device__ __forceinline__ float ldany(const void* p, long long i, int f32){
    return f32 ? ((const float*)p)[i] : b2f(((const bf16*)p)[i]);
}
// explicit round-to-nearest-even fp32->bf16 (error <= 2^-8 relative, guaranteed)
__device__ __forceinline__ unsigned short f2bs(float f){
    unsigned u = __builtin_bit_cast(unsigned, f);
    unsigned r = (u + 0x7FFFu + ((u >> 16) & 1u)) >> 16;
    return (unsigned short)r;
}

// ---------------------------------------------------------------- dtype sniff
__global__ __launch_bounds__(256) void k_sniff(const void* x, const void* wq, int* flags)
{
    __shared__ float red[2][4];
    const unsigned short* xu = (const unsigned short*)x;
    const unsigned short* wu = (const unsigned short*)wq;
    const int tid = threadIdx.x, lane = tid & 63, wvi = tid >> 6;
    float mx = fabsf(u16f(xu[tid]));
    float mw = fabsf(u16f(wu[tid]));
    for (int off = 32; off; off >>= 1){
        mx = fmaxf(mx, __shfl_down(mx, off));
        mw = fmaxf(mw, __shfl_down(mw, off));
    }
    if (lane == 0){ red[0][wvi] = mx; red[1][wvi] = mw; }
    __syncthreads();
    if (tid == 0){
        float ax = fmaxf(fmaxf(red[0][0], red[0][1]), fmaxf(red[0][2], red[0][3]));
        float aw = fmaxf(fmaxf(red[1][0], red[1][1]), fmaxf(red[1][2], red[1][3]));
        flags[0] = (ax > 1e6f) ? 1 : 0;   // p/x family is fp32
        flags[1] = (aw > 1e6f) ? 1 : 0;   // weight family is fp32
    }
}

// ---------------------------------------------------------------- param canonicalization -> fp32 block
struct P20 { const void* p[20]; };

__global__ __launch_bounds__(256) void k_conv_prm(P20 t, const int* __restrict__ flags,
                                                  float* __restrict__ prm)
{
    const int i = blockIdx.x*256 + threadIdx.x;
    if (i >= NPRM) return;
    const int f = flags[1];
    const int sz[20] = {4096,64,4096,64,4096,64,9,3,3,3,192,64,64,64,512,8,8,8,64,8};
    int seg = 0, rem = i;
    while (rem >= sz[seg]){ rem -= sz[seg]; ++seg; }
    prm[i] = ldany(t.p[seg], rem, f);
}

__global__ __launch_bounds__(256) void k_conv_p(const void* __restrict__ p,
                                                const int* __restrict__ flags,
                                                float* __restrict__ p32)
{
    const int i = blockIdx.x*256 + threadIdx.x;
    if (i < NPTS*3) p32[i] = ldany(p, i, flags[0]);
}

// ---------------------------------------------------------------- fp32 -> bf16 feature buffer (once per feature matrix)
__global__ __launch_bounds__(256) void k_conv_feat(const float* __restrict__ src,
                                                   unsigned short* __restrict__ dst)
{
    const int i = (blockIdx.x*256 + threadIdx.x)*4;
    float4 v = *(const float4*)&src[i];
    ushort4 o;
    o.x = f2bs(v.x); o.y = f2bs(v.y); o.z = f2bs(v.z); o.w = f2bs(v.w);
    *(ushort4*)&dst[i] = o;
}

// ---------------------------------------------------------------- projections
__global__ __launch_bounds__(256) void k_proj(
    const void* __restrict__ x, const int* __restrict__ flags,
    const float* __restrict__ prm,
    float* __restrict__ xq, float* __restrict__ xk, float* __restrict__ xv,
    float* __restrict__ sqk, float* __restrict__ sqv)
{
    __shared__ float WQ[4096], WK[4096], WV[4096], BQ[64], BK[64], BV[64];
    const int tid = threadIdx.x;
    for (int i = tid; i < 4096; i += 256){
        WQ[i] = prm[O_WQ+i]; WK[i] = prm[O_WK+i]; WV[i] = prm[O_WV+i];
    }
    if (tid < 64){ BQ[tid]=prm[O_BQ+tid]; BK[tid]=prm[O_BK+tid]; BV[tid]=prm[O_BV+tid]; }
    const int f32 = flags[0];
    __syncthreads();
    const int lane = tid & 63, wvi = tid >> 6;
    const int pt = blockIdx.x*4 + wvi;
    float xl = ldany(x, (long long)pt*64 + lane, f32);
    float aq = BQ[lane], ak = BK[lane], av = BV[lane];
    #pragma unroll
    for (int k = 0; k < 64; ++k){
        float xb = __shfl(xl, k);
        aq += xb*WQ[k*64+lane];
        ak += xb*WK[k*64+lane];
        av += xb*WV[k*64+lane];
    }
    xq[pt*64+lane]=aq; xk[pt*64+lane]=ak; xv[pt*64+lane]=av;
    float s1 = ak*ak, s2 = av*av;
    for (int off=32; off; off>>=1){ s1 += __shfl_down(s1,off); s2 += __shfl_down(s2,off); }
    if (lane==0){ sqk[pt]=s1; sqv[pt]=s2; }
}

// ---------------------------------------------------------------- KNN partial: MFMA filter + exact rescore
// grid 1024: b = bid>>7, qt = (bid>>1)&63, cs = bid&1.
// Block: 64 queries vs 2048 candidates (32 chunks of 64).
// bf16 features pre-converted (featb) -> B-fragments via direct ds_read_b128, zero hot-loop conversion.
// Approx dists filter (margin 2^-5 vs 2^-8 error bound); hits rescored on the owner lane with the
// SEQUENTIAL k=0..63 fp32 chain (global fp32 rows) — bit-identical to the round-8/11 passing arithmetic.
__global__ __launch_bounds__(256) void k_knn_part(
    const float* __restrict__ feat, const unsigned short* __restrict__ featb,
    const float* __restrict__ sq,
    float* __restrict__ pdist, int* __restrict__ pidx)
{
    __shared__ __attribute__((aligned(16))) short Cb[64*72];   // bf16 candidate tile
    __shared__ __attribute__((aligned(16))) float Df[64*68];   // margin-adjusted approx dists
    __shared__ float sqC[64];
    const int tid = threadIdx.x;
    const int b  = blockIdx.x >> 7;
    const int qt = (blockIdx.x >> 1) & 63;
    const int cs = blockIdx.x & 1;
    const int q0 = b*NPB + qt*64;
    const int c00 = b*NPB + cs*2048;
    const int lane = tid & 63, wv = tid >> 6;
    // --- MFMA A fragments (bf16 of this wave's 16-query slab), chunk-invariant
    const int am = lane & 15, aq4 = lane >> 4;     // A row (slab-local), k-quad
    const unsigned short* qrowb = featb + (size_t)(q0 + wv*16 + am)*64 + aq4*8;
    bf16x8 a0 = *(const bf16x8*)qrowb;
    bf16x8 a1 = *(const bf16x8*)(qrowb + 32);
    // --- selection mapping: group of 4 lanes per query; owner (sub==0) does exact rescore
    const int selq = wv*16 + (lane >> 2);
    const int sub  = lane & 3;
    const int owner = lane & ~3;
    const float* qrow_ex = feat + (size_t)(q0 + selq)*64;   // exact fp32 q row (global, L1-hot)
    const float sqqm = sq[q0 + selq] * 0.03125f;     // ||q||^2 * 2^-5 margin (query part)
    const float C1 = 0.96875f;                       // 1 - 2^-5  (candidate part baked into Df)
    float dl[16]; int il[16];
    #pragma unroll
    for (int i=0;i<16;++i){ dl[i] = 3.4e38f; il[i] = 0; }
    for (int chn = 0; chn < 32; ++chn){
        const int c0 = c00 + chn*64;
        // stage bf16 candidate tile: 64 rows x 128B = 8KB; 2 x 16B per thread
        #pragma unroll
        for (int f = tid; f < 512; f += 256){
            int r = f >> 3, s8 = f & 7;
            *(int4*)&Cb[r*72 + s8*8] = *(const int4*)&featb[(size_t)(c0+r)*64 + s8*8];
        }
        if (tid < 64) sqC[tid] = sq[c0 + tid];
        __syncthreads();
        // --- approx distance GEMM on the matrix pipe (B-fragments straight from LDS)
        f32x4 acc0 = {0.f,0.f,0.f,0.f}, acc1 = acc0, acc2 = acc0, acc3 = acc0;
        {
            const short* b0 = &Cb[(0*16 + am)*72 + aq4*8];
            const short* b1 = &Cb[(1*16 + am)*72 + aq4*8];
            const short* b2 = &Cb[(2*16 + am)*72 + aq4*8];
            const short* b3 = &Cb[(3*16 + am)*72 + aq4*8];
            acc0 = __builtin_amdgcn_mfma_f32_16x16x32_bf16(a0, *(const bf16x8*)b0,      acc0, 0,0,0);
            acc0 = __builtin_amdgcn_mfma_f32_16x16x32_bf16(a1, *(const bf16x8*)(b0+32), acc0, 0,0,0);
            acc1 = __builtin_amdgcn_mfma_f32_16x16x32_bf16(a0, *(const bf16x8*)b1,      acc1, 0,0,0);
            acc1 = __builtin_amdgcn_mfma_f32_16x16x32_bf16(a1, *(const bf16x8*)(b1+32), acc1, 0,0,0);
            acc2 = __builtin_amdgcn_mfma_f32_16x16x32_bf16(a0, *(const bf16x8*)b2,      acc2, 0,0,0);
            acc2 = __builtin_amdgcn_mfma_f32_16x16x32_bf16(a1, *(const bf16x8*)(b2+32), acc2, 0,0,0);
            acc3 = __builtin_amdgcn_mfma_f32_16x16x32_bf16(a0, *(const bf16x8*)b3,      acc3, 0,0,0);
            acc3 = __builtin_amdgcn_mfma_f32_16x16x32_bf16(a1, *(const bf16x8*)(b3+32), acc3, 0,0,0);
        }
        // --- dist epilogue: Df[row][col] = sqC[col]*(1-2^-5) - 2*acc  (C/D: col=lane&15, row=quad*4+reg)
        {
            const int rbase = wv*16 + aq4*4;
            float sc0v = sqC[0*16+am]*C1, sc1v = sqC[1*16+am]*C1;
            float sc2v = sqC[2*16+am]*C1, sc3v = sqC[3*16+am]*C1;
            #pragma unroll
            for (int r=0;r<4;++r){
                Df[(rbase+r)*68 + 0*16+am] = sc0v - 2.f*acc0[r];
                Df[(rbase+r)*68 + 1*16+am] = sc1v - 2.f*acc1[r];
                Df[(rbase+r)*68 + 2*16+am] = sc2v - 2.f*acc2[r];
                Df[(rbase+r)*68 + 3*16+am] = sc3v - 2.f*acc3[r];
            }
        }
        __syncthreads();
        // --- cooperative mask build: 4 lanes/query test approx dists vs worst + margin
        float worst = __shfl(dl[15], owner);
        float thr = worst + sqqm;
        unsigned m16 = 0;
        const int rowoff = selq*68 + sub*16;
        #pragma unroll
        for (int r = 0; r < 4; ++r){
            float4 v = *(const float4*)&Df[rowoff + 4*r];
            m16 |= (v.x < thr ? 1u : 0u) << (4*r+0);
            m16 |= (v.y < thr ? 1u : 0u) << (4*r+1);
            m16 |= (v.z < thr ? 1u : 0u) << (4*r+2);
            m16 |= (v.w < thr ? 1u : 0u) << (4*r+3);
        }
        unsigned ma = __shfl(m16, owner+0), mb = __shfl(m16, owner+1);
        unsigned mc = __shfl(m16, owner+2), md = __shfl(m16, owner+3);
        if (sub == 0){
            unsigned long long m = (unsigned long long)ma
                                 | ((unsigned long long)mb << 16)
                                 | ((unsigned long long)mc << 32)
                                 | ((unsigned long long)md << 48);
            while (m){
                int c = (int)__builtin_ctzll(m); m &= m - 1;
                // exact fp32 rescore — SEQUENTIAL k=0..63 chain from global fp32 rows,
                // bit-identical to round-8/11 arithmetic
                const float* cr = feat + (size_t)(c0 + c)*64;
                float acc = 0.f;
                #pragma unroll
                for (int k4 = 0; k4 < 16; ++k4){
                    float4 qv = *(const float4*)(qrow_ex + 4*k4);
                    float4 cv = *(const float4*)(cr + 4*k4);
                    acc += qv.x*cv.x;
                    acc += qv.y*cv.y;
                    acc += qv.z*cv.z;
                    acc += qv.w*cv.w;
                }
                float dex = sqC[c] - 2.f*acc;
                if (dex < dl[15]){
                    int gi = c0 + c;
                    #pragma unroll
                    for (int i = 15; i >= 1; --i){
                        bool sh   = dl[i-1] > dex;
                        bool here = !sh && (dl[i] > dex);
                        dl[i] = sh ? dl[i-1] : (here ? dex : dl[i]);
                        il[i] = sh ? il[i-1] : (here ? gi  : il[i]);
                    }
                    bool h0 = dl[0] > dex;
                    dl[0] = h0 ? dex : dl[0];
                    il[0] = h0 ? gi  : il[0];
                }
            }
        }
        __syncthreads();
    }
    if (sub == 0){
        const size_t base = ((size_t)(q0+selq)*2 + cs)*16;
        #pragma unroll
        for (int i=0;i<16;++i){ pdist[base+i] = dl[i]; pidx[base+i] = il[i]; }
    }
}

// ---------------------------------------------------------------- KNN merge: 2 sorted 16-lists -> top-16
// Stable lexicographic (dist, idx) merge == jax.lax.top_k tie order.
// do_stats=1: also accumulate BN1 h-statistics over the merged neighbors.
__global__ __launch_bounds__(64) void k_knn_merge(
    const float* __restrict__ pdist, const int* __restrict__ pidx, int* __restrict__ idx_out,
    const float* __restrict__ p32, const float* __restrict__ prm,
    float* __restrict__ part1, int do_stats)
{
    __shared__ float D[64][33];
    __shared__ int   I[64][33];
    const int tid = threadIdx.x;
    const size_t gq = (size_t)blockIdx.x*64 + tid;
    #pragma unroll
    for (int j4 = 0; j4 < 8; ++j4){
        float4 dv = *(const float4*)&pdist[gq*32 + 4*j4];
        int4   iv = *(const int4*)  &pidx [gq*32 + 4*j4];
        D[tid][4*j4+0]=dv.x; D[tid][4*j4+1]=dv.y; D[tid][4*j4+2]=dv.z; D[tid][4*j4+3]=dv.w;
        I[tid][4*j4+0]=iv.x; I[tid][4*j4+1]=iv.y; I[tid][4*j4+2]=iv.z; I[tid][4*j4+3]=iv.w;
    }
    int mi[16];
    int p0 = 0, p1 = 16;
    #pragma unroll
    for (int o = 0; o < 16; ++o){
        float d0 = D[tid][p0], d1 = D[tid][p1];
        int   i0 = I[tid][p0], i1 = I[tid][p1];
        bool take1 = (d1 < d0) || (d1 == d0 && i1 < i0);
        mi[o] = take1 ? i1 : i0;
        if (take1) ++p1; else ++p0;
    }
    #pragma unroll
    for (int o4 = 0; o4 < 4; ++o4)
        *(int4*)&idx_out[gq*16 + 4*o4] = make_int4(mi[4*o4], mi[4*o4+1], mi[4*o4+2], mi[4*o4+3]);
    if (!do_stats) return;
    const float w00=prm[O_WP1+0], w01=prm[O_WP1+1], w02=prm[O_WP1+2];
    const float w10=prm[O_WP1+3], w11=prm[O_WP1+4], w12=prm[O_WP1+5];
    const float w20=prm[O_WP1+6], w21=prm[O_WP1+7], w22=prm[O_WP1+8];
    const float bb0=prm[O_BP1+0], bb1=prm[O_BP1+1], bb2=prm[O_BP1+2];
    const float px=p32[gq*3+0], py=p32[gq*3+1], pz=p32[gq*3+2];
    float s0=0.f,s1=0.f,s2=0.f,t0=0.f,t1=0.f,t2=0.f;
    #pragma unroll
    for (int o = 0; o < 16; ++o){
        const int j = mi[o] & IMASK;
        float rx = p32[j*3+0]-px, ry = p32[j*3+1]-py, rz = p32[j*3+2]-pz;
        float h0 = bb0 + rx*w00 + ry*w10 + rz*w20;
        float h1 = bb1 + rx*w01 + ry*w11 + rz*w21;
        float h2 = bb2 + rx*w02 + ry*w12 + rz*w22;
        s0+=h0; s1+=h1; s2+=h2; t0+=h0*h0; t1+=h1*h1; t2+=h2*h2;
    }
    for (int off=32; off; off>>=1){
        s0+=__shfl_down(s0,off); s1+=__shfl_down(s1,off); s2+=__shfl_down(s2,off);
        t0+=__shfl_down(t0,off); t1+=__shfl_down(t1,off); t2+=__shfl_down(t2,off);
    }
    if (tid == 0){
        float* pp = part1 + blockIdx.x*6;
        pp[0]=s0; pp[1]=s1; pp[2]=s2; pp[3]=t0; pp[4]=t1; pp[5]=t2;
    }
}

// ---------------------------------------------------------------- BN partial reduce -> affine
__global__ __launch_bounds__(256) void k_bnred(
    const float* __restrict__ part, int G, int C,
    const float* __restrict__ gamma, const float* __restrict__ beta,
    float* __restrict__ aff, float invCount)
{
    __shared__ float tot[128];
    const int tid = threadIdx.x, lane = tid & 63, wvi = tid >> 6;
    const int S = 2*C;
    for (int s = wvi; s < S; s += 4){
        float v = 0.f;
        for (int idx = lane; idx < G; idx += 64) v += part[(size_t)idx*S + s];
        for (int off=32; off; off>>=1) v += __shfl_down(v, off);
        if (lane == 0) tot[s] = v;
    }
    __syncthreads();
    if (tid < C){
        float mean = tot[tid]*invCount;
        float var  = fmaxf(tot[C+tid]*invCount - mean*mean, 0.f);
        float sc = gamma[tid] * rsqrtf(var + EPSB);
        aff[tid]   = sc;
        aff[C+tid] = beta[tid] - mean*sc;
    }
}

// ---------------------------------------------------------------- BN2 stats over r (unrolled x4)
__global__ __launch_bounds__(256) void k_rstats(
    const float* __restrict__ p32,
    const float* __restrict__ xq, const float* __restrict__ xk, const int* __restrict__ idx_k,
    const float* __restrict__ bn1aff, const float* __restrict__ prm,
    float* __restrict__ part2)
{
    const int tid = threadIdx.x, lane = tid & 63, wvi = tid >> 6;
    const float wa = prm[O_WP2+lane], wb = prm[O_WP2+64+lane], wc = prm[O_WP2+128+lane];
    const float bpc = prm[O_BP2+lane];
    const float w00=prm[O_WP1+0], w01=prm[O_WP1+1], w02=prm[O_WP1+2];
    const float w10=prm[O_WP1+3], w11=prm[O_WP1+4], w12=prm[O_WP1+5];
    const float w20=prm[O_WP1+6], w21=prm[O_WP1+7], w22=prm[O_WP1+8];
    const float bb0=prm[O_BP1+0], bb1=prm[O_BP1+1], bb2=prm[O_BP1+2];
    const float sc0=bn1aff[0], sc1=bn1aff[1], sc2=bn1aff[2];
    const float sh0=bn1aff[3], sh1=bn1aff[4], sh2=bn1aff[5];
    const int base = (blockIdx.x*4 + wvi) * 64;
    float asum=0.f, asq=0.f;
    float px=0.f, py=0.f, pz=0.f, xql=0.f;
    for (int e4 = 0; e4 < 16; ++e4){
        const int gb = base + e4*4;
        if ((gb & 15) == 0){
            const int n = gb >> 4;
            px=p32[n*3+0]; py=p32[n*3+1]; pz=p32[n*3+2];
            xql = xq[(size_t)n*64+lane];
        }
        int4 jj = *(const int4*)&idx_k[gb];
        int j[4] = { jj.x & IMASK, jj.y & IMASK, jj.z & IMASK, jj.w & IMASK };
        float kx[4], qx[4][3];
        #pragma unroll
        for (int u=0;u<4;++u){
            qx[u][0]=p32[j[u]*3+0]; qx[u][1]=p32[j[u]*3+1]; qx[u][2]=p32[j[u]*3+2];
            kx[u] = xk[(size_t)j[u]*64+lane];
        }
        #pragma unroll
        for (int u=0;u<4;++u){
            float rx = qx[u][0]-px, ry = qx[u][1]-py, rz = qx[u][2]-pz;
            float h0 = bb0 + rx*w00 + ry*w10 + rz*w20;
            float h1 = bb1 + rx*w01 + ry*w11 + rz*w21;
            float h2 = bb2 + rx*w02 + ry*w12 + rz*w22;
            float r0 = fmaxf(h0*sc0+sh0, 0.f), r1 = fmaxf(h1*sc1+sh1,0.f), r2 = fmaxf(h2*sc2+sh2,0.f);
            float pr = r0*wa + r1*wb + r2*wc + bpc;
            float rv = kx[u] - xql + pr;
            asum += rv; asq += rv*rv;
        }
    }
    __shared__ float red[4][128];
    red[wvi][lane] = asum; red[wvi][64+lane] = asq;
    __syncthreads();
    if (tid < 128) part2[(size_t)blockIdx.x*128 + tid] = red[0][tid]+red[1][tid]+red[2][tid]+red[3][tid];
}

// ---------------------------------------------------------------- BN3 stats over w (+ wbuf store)
__global__ __launch_bounds__(256) void k_wstats(
    const float* __restrict__ p32,
    const float* __restrict__ xq, const float* __restrict__ xk, const int* __restrict__ idx_k,
    const float* __restrict__ bn1aff, const float* __restrict__ prm,
    const float* __restrict__ bn2aff, float* __restrict__ wbuf, float* __restrict__ part3)
{
    __shared__ float4 PRW[64];
    __shared__ float2 SS2[64];
    __shared__ float4 W1A[64], W1B[64];
    const int tid = threadIdx.x;
    if (tid < 64){
        PRW[tid] = make_float4(prm[O_WP2+tid], prm[O_WP2+64+tid], prm[O_WP2+128+tid], prm[O_BP2+tid]);
        SS2[tid] = make_float2(bn2aff[tid], bn2aff[64+tid]);
        W1A[tid] = make_float4(prm[O_WW1+tid*8+0],prm[O_WW1+tid*8+1],prm[O_WW1+tid*8+2],prm[O_WW1+tid*8+3]);
        W1B[tid] = make_float4(prm[O_WW1+tid*8+4],prm[O_WW1+tid*8+5],prm[O_WW1+tid*8+6],prm[O_WW1+tid*8+7]);
    }
    __syncthreads();
    const int g = blockIdx.x*256 + tid;
    const int n = g >> 4;
    const int j = idx_k[g] & IMASK;
    const float w00=prm[O_WP1+0], w01=prm[O_WP1+1], w02=prm[O_WP1+2];
    const float w10=prm[O_WP1+3], w11=prm[O_WP1+4], w12=prm[O_WP1+5];
    const float w20=prm[O_WP1+6], w21=prm[O_WP1+7], w22=prm[O_WP1+8];
    const float bb0=prm[O_BP1+0], bb1=prm[O_BP1+1], bb2=prm[O_BP1+2];
    const float sc0=bn1aff[0], sc1=bn1aff[1], sc2=bn1aff[2];
    const float sh0=bn1aff[3], sh1=bn1aff[4], sh2=bn1aff[5];
    float rx = p32[j*3+0] - p32[n*3+0];
    float ry = p32[j*3+1] - p32[n*3+1];
    float rz = p32[j*3+2] - p32[n*3+2];
    float h0 = bb0 + rx*w00 + ry*w10 + rz*w20;
    float h1 = bb1 + rx*w01 + ry*w11 + rz*w21;
    float h2 = bb2 + rx*w02 + ry*w12 + rz*w22;
    float r0 = fmaxf(h0*sc0+sh0, 0.f), r1 = fmaxf(h1*sc1+sh1,0.f), r2 = fmaxf(h2*sc2+sh2,0.f);
    float wacc[8];
    #pragma unroll
    for (int i=0;i<8;++i) wacc[i] = prm[O_BW1+i];
    const float4* kr = (const float4*)(xk + (size_t)j*64);
    const float4* qr = (const float4*)(xq + (size_t)n*64);
    #pragma unroll
    for (int c4=0;c4<16;++c4){
        float4 kv = kr[c4], qv = qr[c4];
        float kvv[4] = {kv.x,kv.y,kv.z,kv.w};
        float qvv[4] = {qv.x,qv.y,qv.z,qv.w};
        #pragma unroll
        for (int d=0; d<4; ++d){
            int c = 4*c4 + d;
            float4 pw = PRW[c]; float2 ss = SS2[c];
            float pr = r0*pw.x + r1*pw.y + r2*pw.z + pw.w;
            float rr = kvv[d] - qvv[d] + pr;
            float y = fmaxf(rr*ss.x + ss.y, 0.f);
            float4 wA = W1A[c], wB = W1B[c];
            wacc[0]+=y*wA.x; wacc[1]+=y*wA.y; wacc[2]+=y*wA.z; wacc[3]+=y*wA.w;
            wacc[4]+=y*wB.x; wacc[5]+=y*wB.y; wacc[6]+=y*wB.z; wacc[7]+=y*wB.w;
        }
    }
    *(float4*)&wbuf[(size_t)g*8]   = make_float4(wacc[0],wacc[1],wacc[2],wacc[3]);
    *(float4*)&wbuf[(size_t)g*8+4] = make_float4(wacc[4],wacc[5],wacc[6],wacc[7]);
    float st[16];
    #pragma unroll
    for (int i=0;i<8;++i){ st[i]=wacc[i]; st[8+i]=wacc[i]*wacc[i]; }
    for (int off=32; off; off>>=1){
        #pragma unroll
        for (int k=0;k<16;++k) st[k] += __shfl_down(st[k], off);
    }
    __shared__ float red[4][16];
    const int lane = tid&63, wvi = tid>>6;
    if (lane==0){
        #pragma unroll
        for (int k=0;k<16;++k) red[wvi][k]=st[k];
    }
    __syncthreads();
    if (tid < 16) part3[(size_t)blockIdx.x*16 + tid] = red[0][tid]+red[1][tid]+red[2][tid]+red[3][tid];
}

// ---------------------------------------------------------------- final (reads wbuf; no shfl chain)
__global__ __launch_bounds__(256) void k_out(
    const float* __restrict__ p32, const float* __restrict__ xv,
    const int* __restrict__ idx_k, const int* __restrict__ idx_v,
    const float* __restrict__ bn1aff, const float* __restrict__ prm,
    const float* __restrict__ wbuf, const float* __restrict__ bn3aff,
    const int* __restrict__ flags, void* __restrict__ out)
{
    const int tid = threadIdx.x, lane = tid & 63, wvi = tid >> 6;
    const int n = blockIdx.x*4 + wvi;
    const int f32 = flags[0];
    const float w00=prm[O_WP1+0], w01=prm[O_WP1+1], w02=prm[O_WP1+2];
    const float w10=prm[O_WP1+3], w11=prm[O_WP1+4], w12=prm[O_WP1+5];
    const float w20=prm[O_WP1+6], w21=prm[O_WP1+7], w22=prm[O_WP1+8];
    const float bb0=prm[O_BP1+0], bb1=prm[O_BP1+1], bb2=prm[O_BP1+2];
    const float sc0=bn1aff[0], sc1=bn1aff[1], sc2=bn1aff[2];
    const float sh0=bn1aff[3], sh1=bn1aff[4], sh2=bn1aff[5];
    const float wa=prm[O_WP2+lane], wb=prm[O_WP2+64+lane], wc=prm[O_WP2+128+lane];
    const float bpc=prm[O_BP2+lane];
    const int i = lane & 7;
    float s3[8], t3[8], w2col[8];
    #pragma unroll
    for (int m=0;m<8;++m){
        s3[m]=bn3aff[m]; t3[m]=bn3aff[8+m];
        w2col[m]=prm[O_WW2+m*8+i];
    }
    const float bw2i = prm[O_BW2+i];
    const float px=p32[n*3+0], py=p32[n*3+1], pz=p32[n*3+2];
    float comb[16], wf[16];
    #pragma unroll
    for (int t=0;t<16;++t){
        const int g = n*16 + t;
        const int jk = idx_k[g] & IMASK;
        const int jv = idx_v[g] & IMASK;
        float rx=p32[jk*3+0]-px, ry=p32[jk*3+1]-py, rz=p32[jk*3+2]-pz;
        float h0=bb0+rx*w00+ry*w10+rz*w20;
        float h1=bb1+rx*w01+ry*w11+rz*w21;
        float h2=bb2+rx*w02+ry*w12+rz*w22;
        float r0=fmaxf(h0*sc0+sh0,0.f), r1=fmaxf(h1*sc1+sh1,0.f), r2=fmaxf(h2*sc2+sh2,0.f);
        float pr=r0*wa+r1*wb+r2*wc+bpc;
        float4 wA = *(const float4*)&wbuf[(size_t)g*8];
        float4 wB = *(const float4*)&wbuf[(size_t)g*8+4];
        float wm[8] = {wA.x,wA.y,wA.z,wA.w,wB.x,wB.y,wB.z,wB.w};
        float acc = bw2i;
        #pragma unroll
        for (int m=0;m<8;++m){
            float y3 = fmaxf(wm[m]*s3[m]+t3[m],0.f);
            acc += y3*w2col[m];
        }
        wf[t]=acc;
        comb[t]=xv[(size_t)jv*64+lane]+pr;
    }
    float mx = wf[0];
    #pragma unroll
    for (int t=1;t<16;++t) mx = fmaxf(mx, wf[t]);
    float ssum=0.f, osum=0.f;
    #pragma unroll
    for (int t=0;t<16;++t){ float e = __expf(wf[t]-mx); ssum += e; osum += e*comb[t]; }
    const float v = osum / ssum;
    if (f32) ((float*)out)[(size_t)n*64+lane] = v;
    else     ((bf16*)out)[(size_t)n*64+lane] = __float2bfloat16(v);
}

// ---------------------------------------------------------------- launcher
extern "C" void kernel_launch(void* const* d_in, const int* in_sizes, int n_in,
                              void* d_out, int out_size, void* d_ws, size_t ws_size,
                              hipStream_t stream)
{
    const void* p  = d_in[0];
    const void* x  = d_in[1];
    P20 prms;
    for (int i = 0; i < 20; ++i) prms.p[i] = d_in[3+i];

    // workspace layout (floats) — peak 12,019,056 floats = 48.08 MB (proven)
    float* W = (float*)d_ws;
    float* xqf    = W + 0;
    float* xkf    = W + 2097152;
    float* xvf    = W + 4194304;
    float* sqk    = W + 6291456;
    float* sqv    = W + 6324224;
    int*   idx_k  = (int*)(W + 6356992);
    int*   idx_v  = (int*)(W + 6881280);
    float* p32    = W + 7405568;   // 98304
    float* prm    = W + 7503872;   // 13490 (+pad)
    float* part1  = W + 7517376;   // 512*6 (slack)
    float* part2  = W + 7529664;   // 2048*128
    float* part3  = W + 7791808;   // 2048*16
    float* bn1aff = W + 7824576;   // 16
    float* bn2aff = W + 7824592;   // 128
    float* bn3aff = W + 7824720;   // 16
    int*   flags  = (int*)(W + 7824736); // 2 (+pad to 16)
    float* pdist  = W + 7824752;   // 1,048,576 floats (dead after merges)
    int*   pidx   = (int*)(W + 8873328);  // 1,048,576 ints (dead after merges)
    unsigned short* featb = (unsigned short*)(W + 9921904); // 2,097,152 bf16 = 1,048,576 float-slots
                                   // (dead after 2nd knn; inside wbuf region, written before wbuf)
    float* wbuf   = W + 7824752;   // 4,194,304 — overlays pdist+pidx+featb (written after merges)

    const float invP = 1.f / (float)NPAIR;

    k_sniff<<<1,256,0,stream>>>(x, d_in[3], flags);
    k_conv_prm<<<(NPRM+255)/256,256,0,stream>>>(prms, flags, prm);
    k_conv_p<<<(NPTS*3+255)/256,256,0,stream>>>(p, flags, p32);
    k_proj<<<8192,256,0,stream>>>(x, flags, prm, xqf,xkf,xvf, sqk,sqv);
    k_conv_feat<<<2048,256,0,stream>>>(xkf, featb);
    k_knn_part <<<1024,256,0,stream>>>(xkf, featb, sqk, pdist, pidx);
    k_knn_merge<<<512,64,0,stream>>>(pdist, pidx, idx_k, p32, prm, part1, 1);
    k_conv_feat<<<2048,256,0,stream>>>(xvf, featb);
    k_knn_part <<<1024,256,0,stream>>>(xvf, featb, sqv, pdist, pidx);
    k_knn_merge<<<512,64,0,stream>>>(pdist, pidx, idx_v, p32, prm, part1, 0);
    k_bnred<<<1,256,0,stream>>>(part1, 512, 3, prm+O_GP, prm+O_BTP, bn1aff, invP);
    k_rstats<<<2048,256,0,stream>>>(p32, xqf, xkf, idx_k, bn1aff, prm, part2);
    k_bnred<<<1,256,0,stream>>>(part2, 2048, 64, prm+O_G1, prm+O_BT1, bn2aff, invP);
    k_wstats<<<2048,256,0,stream>>>(p32, xqf, xkf, idx_k, bn1aff, prm, bn2aff, wbuf, part3);
    k_bnred<<<1,256,0,stream>>>(part3, 2048, 8, prm+O_G2, prm+O_BT2, bn3aff, invP);
    k_out<<<8192,256,0,stream>>>(p32, xvf, idx_k, idx_v, bn1aff, prm,
                                 wbuf, bn3aff, flags, d_out);
}

// Round 13
// 1276.140 us; speedup vs baseline: 1.5513x; 1.5513x over previous
//
#include <hip/hip_runtime.h>
#include <hip/hip_bf16.h>

typedef __hip_bfloat16 bf16;

#define NPTS  32768
#define NPB   4096
#define NPAIR (NPTS*16)
#define IMASK 32767
#define EPSB  1e-5f

// packed fp32 param-block offsets (floats)
#define O_WQ  0
#define O_BQ  4096
#define O_WK  4160
#define O_BK  8256
#define O_WV  8320
#define O_BV  12416
#define O_WP1 12480
#define O_BP1 12489
#define O_GP  12492
#define O_BTP 12495
#define O_WP2 12498
#define O_BP2 12690
#define O_G1  12754
#define O_BT1 12818
#define O_WW1 12882
#define O_BW1 13394
#define O_G2  13402
#define O_BT2 13410
#define O_WW2 13418
#define O_BW2 13482
#define NPRM  13490

__device__ __forceinline__ float b2f(bf16 v){ return __bfloat162float(v); }
__device__ __forceinline__ float u16f(unsigned short u){ return __uint_as_float(((unsigned)u)<<16); }
__device__ __forceinline__ float ldany(const void* p, long long i, int f32){
    return f32 ? ((const float*)p)[i] : b2f(((const bf16*)p)[i]);
}

// ---------------------------------------------------------------- dtype sniff
__global__ __launch_bounds__(256) void k_sniff(const void* x, const void* wq, int* flags)
{
    __shared__ float red[2][4];
    const unsigned short* xu = (const unsigned short*)x;
    const unsigned short* wu = (const unsigned short*)wq;
    const int tid = threadIdx.x, lane = tid & 63, wvi = tid >> 6;
    float mx = fabsf(u16f(xu[tid]));
    float mw = fabsf(u16f(wu[tid]));
    for (int off = 32; off; off >>= 1){
        mx = fmaxf(mx, __shfl_down(mx, off));
        mw = fmaxf(mw, __shfl_down(mw, off));
    }
    if (lane == 0){ red[0][wvi] = mx; red[1][wvi] = mw; }
    __syncthreads();
    if (tid == 0){
        float ax = fmaxf(fmaxf(red[0][0], red[0][1]), fmaxf(red[0][2], red[0][3]));
        float aw = fmaxf(fmaxf(red[1][0], red[1][1]), fmaxf(red[1][2], red[1][3]));
        flags[0] = (ax > 1e6f) ? 1 : 0;   // p/x family is fp32
        flags[1] = (aw > 1e6f) ? 1 : 0;   // weight family is fp32
    }
}

// ---------------------------------------------------------------- param canonicalization -> fp32 block
struct P20 { const void* p[20]; };

__global__ __launch_bounds__(256) void k_conv_prm(P20 t, const int* __restrict__ flags,
                                                  float* __restrict__ prm)
{
    const int i = blockIdx.x*256 + threadIdx.x;
    if (i >= NPRM) return;
    const int f = flags[1];
    const int sz[20] = {4096,64,4096,64,4096,64,9,3,3,3,192,64,64,64,512,8,8,8,64,8};
    int seg = 0, rem = i;
    while (rem >= sz[seg]){ rem -= sz[seg]; ++seg; }
    prm[i] = ldany(t.p[seg], rem, f);
}

__global__ __launch_bounds__(256) void k_conv_p(const void* __restrict__ p,
                                                const int* __restrict__ flags,
                                                float* __restrict__ p32)
{
    const int i = blockIdx.x*256 + threadIdx.x;
    if (i < NPTS*3) p32[i] = ldany(p, i, flags[0]);
}

// ---------------------------------------------------------------- projections (16 pts/block: weight staging amortized 4x)
__global__ __launch_bounds__(256) void k_proj(
    const void* __restrict__ x, const int* __restrict__ flags,
    const float* __restrict__ prm,
    float* __restrict__ xq, float* __restrict__ xk, float* __restrict__ xv,
    float* __restrict__ sqk, float* __restrict__ sqv)
{
    __shared__ float WQ[4096], WK[4096], WV[4096], BQ[64], BK[64], BV[64];
    const int tid = threadIdx.x;
    for (int i = tid; i < 4096; i += 256){
        WQ[i] = prm[O_WQ+i]; WK[i] = prm[O_WK+i]; WV[i] = prm[O_WV+i];
    }
    if (tid < 64){ BQ[tid]=prm[O_BQ+tid]; BK[tid]=prm[O_BK+tid]; BV[tid]=prm[O_BV+tid]; }
    const int f32 = flags[0];
    __syncthreads();
    const int lane = tid & 63, wvi = tid >> 6;
    const int ptbase = blockIdx.x*16 + wvi*4;
    for (int it = 0; it < 4; ++it){
        const int pt = ptbase + it;
        float xl = ldany(x, (long long)pt*64 + lane, f32);
        float aq = BQ[lane], ak = BK[lane], av = BV[lane];
        #pragma unroll
        for (int k = 0; k < 64; ++k){
            float xb = __shfl(xl, k);
            aq += xb*WQ[k*64+lane];
            ak += xb*WK[k*64+lane];
            av += xb*WV[k*64+lane];
        }
        xq[pt*64+lane]=aq; xk[pt*64+lane]=ak; xv[pt*64+lane]=av;
        float s1 = ak*ak, s2 = av*av;
        for (int off=32; off; off>>=1){ s1 += __shfl_down(s1,off); s2 += __shfl_down(s2,off); }
        if (lane==0){ sqk[pt]=s1; sqv[pt]=s2; }
    }
}

// ---------------------------------------------------------------- KNN partial (candidate-split x2; round-8 proven config)
// grid 1024: b = bid>>7, qt = (bid>>1)&63, cs = bid&1.
// Block: 64 queries vs 2048 candidates (32 chunks of 64). Tile 4q x 4c.
// Register top-16 in owner lanes; cooperative 4-lane mask filter.
__global__ __launch_bounds__(256) void k_knn_part(
    const float* __restrict__ feat, const float* __restrict__ sq,
    float* __restrict__ pdist, int* __restrict__ pidx)
{
    __shared__ __attribute__((aligned(16))) float Qf[64*68];
    __shared__ __attribute__((aligned(16))) float Cf[64*68];  // cand tile; reused as dist tile [64][68]
    __shared__ float sqC[64];
    const int tid = threadIdx.x;
    const int b  = blockIdx.x >> 7;
    const int qt = (blockIdx.x >> 1) & 63;
    const int cs = blockIdx.x & 1;
    const int q0 = b*NPB + qt*64;
    const int c00 = b*NPB + cs*2048;
    for (int f = tid; f < 64*16; f += 256){
        int r = f >> 4, c4 = f & 15;
        *(float4*)&Qf[r*68 + 4*c4] = *(const float4*)&feat[(size_t)(q0+r)*64 + 4*c4];
    }
    float dl[16]; int il[16];
    #pragma unroll
    for (int i=0;i<16;++i){ dl[i] = 3.4e38f; il[i] = 0; }
    const int lane = tid & 63, wv = tid >> 6;
    const int qsub = tid & 15, csub = tid >> 4;       // compute-phase mapping
    const int selq = (wv << 4) + (lane >> 2);         // selection row (0..63)
    const int sub  = lane & 3;
    const int owner = lane & ~3;
    __syncthreads();
    for (int chn = 0; chn < 32; ++chn){
        const int c0 = c00 + chn*64;
        for (int f = tid; f < 64*16; f += 256){
            int r = f >> 4, c4 = f & 15;
            *(float4*)&Cf[r*68 + 4*c4] = *(const float4*)&feat[(size_t)(c0+r)*64 + 4*c4];
        }
        if (tid < 64) sqC[tid] = sq[c0 + tid];
        __syncthreads();
        float acc[4][4];
        #pragma unroll
        for (int a=0;a<4;++a)
            #pragma unroll
            for (int e=0;e<4;++e) acc[a][e]=0.f;
        #pragma unroll 4
        for (int k4 = 0; k4 < 16; ++k4){
            float4 qv[4], cv[4];
            #pragma unroll
            for (int a=0;a<4;++a) qv[a] = *(const float4*)&Qf[(qsub+16*a)*68 + 4*k4];
            #pragma unroll
            for (int e=0;e<4;++e) cv[e] = *(const float4*)&Cf[(csub+16*e)*68 + 4*k4];
            #pragma unroll
            for (int a=0;a<4;++a)
                #pragma unroll
                for (int e=0;e<4;++e){
                    acc[a][e] += qv[a].x*cv[e].x;
                    acc[a][e] += qv[a].y*cv[e].y;
                    acc[a][e] += qv[a].z*cv[e].z;
                    acc[a][e] += qv[a].w*cv[e].w;
                }
        }
        __syncthreads();
        #pragma unroll
        for (int a=0;a<4;++a)
            #pragma unroll
            for (int e=0;e<4;++e){
                int qq = qsub+16*a, cc = csub+16*e;
                Cf[qq*68 + cc] = sqC[cc] - 2.f*acc[a][e];
            }
        __syncthreads();
        // ---- cooperative selection: 4 lanes per query build hit-mask
        float worst = __shfl(dl[15], owner);
        unsigned m16 = 0;
        const int rowoff = selq*68 + sub*16;
        #pragma unroll
        for (int r = 0; r < 4; ++r){
            float4 v = *(const float4*)&Cf[rowoff + 4*r];
            m16 |= (v.x < worst ? 1u : 0u) << (4*r+0);
            m16 |= (v.y < worst ? 1u : 0u) << (4*r+1);
            m16 |= (v.z < worst ? 1u : 0u) << (4*r+2);
            m16 |= (v.w < worst ? 1u : 0u) << (4*r+3);
        }
        unsigned ma = __shfl(m16, owner+0), mb = __shfl(m16, owner+1);
        unsigned mc = __shfl(m16, owner+2), md = __shfl(m16, owner+3);
        if (sub == 0){
            unsigned long long m = (unsigned long long)ma
                                 | ((unsigned long long)mb << 16)
                                 | ((unsigned long long)mc << 32)
                                 | ((unsigned long long)md << 48);
            const int qrow = selq*68;
            while (m){
                int c = (int)__builtin_ctzll(m); m &= m - 1;
                float d = Cf[qrow + c];
                if (d < dl[15]){
                    int gi = c0 + c;
                    #pragma unroll
                    for (int i = 15; i >= 1; --i){
                        bool sh   = dl[i-1] > d;
                        bool here = !sh && (dl[i] > d);
                        dl[i] = sh ? dl[i-1] : (here ? d  : dl[i]);
                        il[i] = sh ? il[i-1] : (here ? gi : il[i]);
                    }
                    bool h0 = dl[0] > d;
                    dl[0] = h0 ? d  : dl[0];
                    il[0] = h0 ? gi : il[0];
                }
            }
        }
        __syncthreads();
    }
    if (sub == 0){
        const size_t base = ((size_t)(q0+selq)*2 + cs)*16;
        #pragma unroll
        for (int i=0;i<16;++i){ pdist[base+i] = dl[i]; pidx[base+i] = il[i]; }
    }
}

// ---------------------------------------------------------------- KNN merge: 2 sorted 16-lists -> top-16
// Stable lexicographic (dist, idx) merge == jax.lax.top_k tie order.
// do_stats=1: also accumulate BN1 h-statistics over the merged neighbors.
__global__ __launch_bounds__(64) void k_knn_merge(
    const float* __restrict__ pdist, const int* __restrict__ pidx, int* __restrict__ idx_out,
    const float* __restrict__ p32, const float* __restrict__ prm,
    float* __restrict__ part1, int do_stats)
{
    __shared__ float D[64][33];
    __shared__ int   I[64][33];
    const int tid = threadIdx.x;
    const size_t gq = (size_t)blockIdx.x*64 + tid;
    #pragma unroll
    for (int j4 = 0; j4 < 8; ++j4){
        float4 dv = *(const float4*)&pdist[gq*32 + 4*j4];
        int4   iv = *(const int4*)  &pidx [gq*32 + 4*j4];
        D[tid][4*j4+0]=dv.x; D[tid][4*j4+1]=dv.y; D[tid][4*j4+2]=dv.z; D[tid][4*j4+3]=dv.w;
        I[tid][4*j4+0]=iv.x; I[tid][4*j4+1]=iv.y; I[tid][4*j4+2]=iv.z; I[tid][4*j4+3]=iv.w;
    }
    int mi[16];
    int p0 = 0, p1 = 16;
    #pragma unroll
    for (int o = 0; o < 16; ++o){
        float d0 = D[tid][p0], d1 = D[tid][p1];
        int   i0 = I[tid][p0], i1 = I[tid][p1];
        bool take1 = (d1 < d0) || (d1 == d0 && i1 < i0);
        mi[o] = take1 ? i1 : i0;
        if (take1) ++p1; else ++p0;
    }
    #pragma unroll
    for (int o4 = 0; o4 < 4; ++o4)
        *(int4*)&idx_out[gq*16 + 4*o4] = make_int4(mi[4*o4], mi[4*o4+1], mi[4*o4+2], mi[4*o4+3]);
    if (!do_stats) return;
    const float w00=prm[O_WP1+0], w01=prm[O_WP1+1], w02=prm[O_WP1+2];
    const float w10=prm[O_WP1+3], w11=prm[O_WP1+4], w12=prm[O_WP1+5];
    const float w20=prm[O_WP1+6], w21=prm[O_WP1+7], w22=prm[O_WP1+8];
    const float bb0=prm[O_BP1+0], bb1=prm[O_BP1+1], bb2=prm[O_BP1+2];
    const float px=p32[gq*3+0], py=p32[gq*3+1], pz=p32[gq*3+2];
    float s0=0.f,s1=0.f,s2=0.f,t0=0.f,t1=0.f,t2=0.f;
    #pragma unroll
    for (int o = 0; o < 16; ++o){
        const int j = mi[o] & IMASK;
        float rx = p32[j*3+0]-px, ry = p32[j*3+1]-py, rz = p32[j*3+2]-pz;
        float h0 = bb0 + rx*w00 + ry*w10 + rz*w20;
        float h1 = bb1 + rx*w01 + ry*w11 + rz*w21;
        float h2 = bb2 + rx*w02 + ry*w12 + rz*w22;
        s0+=h0; s1+=h1; s2+=h2; t0+=h0*h0; t1+=h1*h1; t2+=h2*h2;
    }
    for (int off=32; off; off>>=1){
        s0+=__shfl_down(s0,off); s1+=__shfl_down(s1,off); s2+=__shfl_down(s2,off);
        t0+=__shfl_down(t0,off); t1+=__shfl_down(t1,off); t2+=__shfl_down(t2,off);
    }
    if (tid == 0){
        float* pp = part1 + blockIdx.x*6;
        pp[0]=s0; pp[1]=s1; pp[2]=s2; pp[3]=t0; pp[4]=t1; pp[5]=t2;
    }
}

// ---------------------------------------------------------------- BN partial reduce -> affine
__global__ __launch_bounds__(256) void k_bnred(
    const float* __restrict__ part, int G, int C,
    const float* __restrict__ gamma, const float* __restrict__ beta,
    float* __restrict__ aff, float invCount)
{
    __shared__ float tot[128];
    const int tid = threadIdx.x, lane = tid & 63, wvi = tid >> 6;
    const int S = 2*C;
    for (int s = wvi; s < S; s += 4){
        float v = 0.f;
        for (int idx = lane; idx < G; idx += 64) v += part[(size_t)idx*S + s];
        for (int off=32; off; off>>=1) v += __shfl_down(v, off);
        if (lane == 0) tot[s] = v;
    }
    __syncthreads();
    if (tid < C){
        float mean = tot[tid]*invCount;
        float var  = fmaxf(tot[C+tid]*invCount - mean*mean, 0.f);
        float sc = gamma[tid] * rsqrtf(var + EPSB);
        aff[tid]   = sc;
        aff[C+tid] = beta[tid] - mean*sc;
    }
}

// ---------------------------------------------------------------- BN2 stats over r (unrolled x4)
__global__ __launch_bounds__(256) void k_rstats(
    const float* __restrict__ p32,
    const float* __restrict__ xq, const float* __restrict__ xk, const int* __restrict__ idx_k,
    const float* __restrict__ bn1aff, const float* __restrict__ prm,
    float* __restrict__ part2)
{
    const int tid = threadIdx.x, lane = tid & 63, wvi = tid >> 6;
    const float wa = prm[O_WP2+lane], wb = prm[O_WP2+64+lane], wc = prm[O_WP2+128+lane];
    const float bpc = prm[O_BP2+lane];
    const float w00=prm[O_WP1+0], w01=prm[O_WP1+1], w02=prm[O_WP1+2];
    const float w10=prm[O_WP1+3], w11=prm[O_WP1+4], w12=prm[O_WP1+5];
    const float w20=prm[O_WP1+6], w21=prm[O_WP1+7], w22=prm[O_WP1+8];
    const float bb0=prm[O_BP1+0], bb1=prm[O_BP1+1], bb2=prm[O_BP1+2];
    const float sc0=bn1aff[0], sc1=bn1aff[1], sc2=bn1aff[2];
    const float sh0=bn1aff[3], sh1=bn1aff[4], sh2=bn1aff[5];
    const int base = (blockIdx.x*4 + wvi) * 64;
    float asum=0.f, asq=0.f;
    float px=0.f, py=0.f, pz=0.f, xql=0.f;
    for (int e4 = 0; e4 < 16; ++e4){
        const int gb = base + e4*4;
        if ((gb & 15) == 0){
            const int n = gb >> 4;
            px=p32[n*3+0]; py=p32[n*3+1]; pz=p32[n*3+2];
            xql = xq[(size_t)n*64+lane];
        }
        int4 jj = *(const int4*)&idx_k[gb];
        int j[4] = { jj.x & IMASK, jj.y & IMASK, jj.z & IMASK, jj.w & IMASK };
        float kx[4], qx[4][3];
        #pragma unroll
        for (int u=0;u<4;++u){
            qx[u][0]=p32[j[u]*3+0]; qx[u][1]=p32[j[u]*3+1]; qx[u][2]=p32[j[u]*3+2];
            kx[u] = xk[(size_t)j[u]*64+lane];
        }
        #pragma unroll
        for (int u=0;u<4;++u){
            float rx = qx[u][0]-px, ry = qx[u][1]-py, rz = qx[u][2]-pz;
            float h0 = bb0 + rx*w00 + ry*w10 + rz*w20;
            float h1 = bb1 + rx*w01 + ry*w11 + rz*w21;
            float h2 = bb2 + rx*w02 + ry*w12 + rz*w22;
            float r0 = fmaxf(h0*sc0+sh0, 0.f), r1 = fmaxf(h1*sc1+sh1,0.f), r2 = fmaxf(h2*sc2+sh2,0.f);
            float pr = r0*wa + r1*wb + r2*wc + bpc;
            float rv = kx[u] - xql + pr;
            asum += rv; asq += rv*rv;
        }
    }
    __shared__ float red[4][128];
    red[wvi][lane] = asum; red[wvi][64+lane] = asq;
    __syncthreads();
    if (tid < 128) part2[(size_t)blockIdx.x*128 + tid] = red[0][tid]+red[1][tid]+red[2][tid]+red[3][tid];
}

// ---------------------------------------------------------------- BN3 stats over w (+ wbuf store)
__global__ __launch_bounds__(256) void k_wstats(
    const float* __restrict__ p32,
    const float* __restrict__ xq, const float* __restrict__ xk, const int* __restrict__ idx_k,
    const float* __restrict__ bn1aff, const float* __restrict__ prm,
    const float* __restrict__ bn2aff, float* __restrict__ wbuf, float* __restrict__ part3)
{
    __shared__ float4 PRW[64];
    __shared__ float2 SS2[64];
    __shared__ float4 W1A[64], W1B[64];
    const int tid = threadIdx.x;
    if (tid < 64){
        PRW[tid] = make_float4(prm[O_WP2+tid], prm[O_WP2+64+tid], prm[O_WP2+128+tid], prm[O_BP2+tid]);
        SS2[tid] = make_float2(bn2aff[tid], bn2aff[64+tid]);
        W1A[tid] = make_float4(prm[O_WW1+tid*8+0],prm[O_WW1+tid*8+1],prm[O_WW1+tid*8+2],prm[O_WW1+tid*8+3]);
        W1B[tid] = make_float4(prm[O_WW1+tid*8+4],prm[O_WW1+tid*8+5],prm[O_WW1+tid*8+6],prm[O_WW1+tid*8+7]);
    }
    __syncthreads();
    const int g = blockIdx.x*256 + tid;
    const int n = g >> 4;
    const int j = idx_k[g] & IMASK;
    const float w00=prm[O_WP1+0], w01=prm[O_WP1+1], w02=prm[O_WP1+2];
    const float w10=prm[O_WP1+3], w11=prm[O_WP1+4], w12=prm[O_WP1+5];
    const float w20=prm[O_WP1+6], w21=prm[O_WP1+7], w22=prm[O_WP1+8];
    const float bb0=prm[O_BP1+0], bb1=prm[O_BP1+1], bb2=prm[O_BP1+2];
    const float sc0=bn1aff[0], sc1=bn1aff[1], sc2=bn1aff[2];
    const float sh0=bn1aff[3], sh1=bn1aff[4], sh2=bn1aff[5];
    float rx = p32[j*3+0] - p32[n*3+0];
    float ry = p32[j*3+1] - p32[n*3+1];
    float rz = p32[j*3+2] - p32[n*3+2];
    float h0 = bb0 + rx*w00 + ry*w10 + rz*w20;
    float h1 = bb1 + rx*w01 + ry*w11 + rz*w21;
    float h2 = bb2 + rx*w02 + ry*w12 + rz*w22;
    float r0 = fmaxf(h0*sc0+sh0, 0.f), r1 = fmaxf(h1*sc1+sh1,0.f), r2 = fmaxf(h2*sc2+sh2,0.f);
    float wacc[8];
    #pragma unroll
    for (int i=0;i<8;++i) wacc[i] = prm[O_BW1+i];
    const float4* kr = (const float4*)(xk + (size_t)j*64);
    const float4* qr = (const float4*)(xq + (size_t)n*64);
    #pragma unroll
    for (int c4=0;c4<16;++c4){
        float4 kv = kr[c4], qv = qr[c4];
        float kvv[4] = {kv.x,kv.y,kv.z,kv.w};
        float qvv[4] = {qv.x,qv.y,qv.z,qv.w};
        #pragma unroll
        for (int d=0; d<4; ++d){
            int c = 4*c4 + d;
            float4 pw = PRW[c]; float2 ss = SS2[c];
            float pr = r0*pw.x + r1*pw.y + r2*pw.z + pw.w;
            float rr = kvv[d] - qvv[d] + pr;
            float y = fmaxf(rr*ss.x + ss.y, 0.f);
            float4 wA = W1A[c], wB = W1B[c];
            wacc[0]+=y*wA.x; wacc[1]+=y*wA.y; wacc[2]+=y*wA.z; wacc[3]+=y*wA.w;
            wacc[4]+=y*wB.x; wacc[5]+=y*wB.y; wacc[6]+=y*wB.z; wacc[7]+=y*wB.w;
        }
    }
    *(float4*)&wbuf[(size_t)g*8]   = make_float4(wacc[0],wacc[1],wacc[2],wacc[3]);
    *(float4*)&wbuf[(size_t)g*8+4] = make_float4(wacc[4],wacc[5],wacc[6],wacc[7]);
    float st[16];
    #pragma unroll
    for (int i=0;i<8;++i){ st[i]=wacc[i]; st[8+i]=wacc[i]*wacc[i]; }
    for (int off=32; off; off>>=1){
        #pragma unroll
        for (int k=0;k<16;++k) st[k] += __shfl_down(st[k], off);
    }
    __shared__ float red[4][16];
    const int lane = tid&63, wvi = tid>>6;
    if (lane==0){
        #pragma unroll
        for (int k=0;k<16;++k) red[wvi][k]=st[k];
    }
    __syncthreads();
    if (tid < 16) part3[(size_t)blockIdx.x*16 + tid] = red[0][tid]+red[1][tid]+red[2][tid]+red[3][tid];
}

// ---------------------------------------------------------------- final (reads wbuf; no shfl chain)
__global__ __launch_bounds__(256) void k_out(
    const float* __restrict__ p32, const float* __restrict__ xv,
    const int* __restrict__ idx_k, const int* __restrict__ idx_v,
    const float* __restrict__ bn1aff, const float* __restrict__ prm,
    const float* __restrict__ wbuf, const float* __restrict__ bn3aff,
    const int* __restrict__ flags, void* __restrict__ out)
{
    const int tid = threadIdx.x, lane = tid & 63, wvi = tid >> 6;
    const int n = blockIdx.x*4 + wvi;
    const int f32 = flags[0];
    const float w00=prm[O_WP1+0], w01=prm[O_WP1+1], w02=prm[O_WP1+2];
    const float w10=prm[O_WP1+3], w11=prm[O_WP1+4], w12=prm[O_WP1+5];
    const float w20=prm[O_WP1+6], w21=prm[O_WP1+7], w22=prm[O_WP1+8];
    const float bb0=prm[O_BP1+0], bb1=prm[O_BP1+1], bb2=prm[O_BP1+2];
    const float sc0=bn1aff[0], sc1=bn1aff[1], sc2=bn1aff[2];
    const float sh0=bn1aff[3], sh1=bn1aff[4], sh2=bn1aff[5];
    const float wa=prm[O_WP2+lane], wb=prm[O_WP2+64+lane], wc=prm[O_WP2+128+lane];
    const float bpc=prm[O_BP2+lane];
    const int i = lane & 7;
    float s3[8], t3[8], w2col[8];
    #pragma unroll
    for (int m=0;m<8;++m){
        s3[m]=bn3aff[m]; t3[m]=bn3aff[8+m];
        w2col[m]=prm[O_WW2+m*8+i];
    }
    const float bw2i = prm[O_BW2+i];
    const float px=p32[n*3+0], py=p32[n*3+1], pz=p32[n*3+2];
    float comb[16], wf[16];
    #pragma unroll
    for (int t=0;t<16;++t){
        const int g = n*16 + t;
        const int jk = idx_k[g] & IMASK;
        const int jv = idx_v[g] & IMASK;
        float rx=p32[jk*3+0]-px, ry=p32[jk*3+1]-py, rz=p32[jk*3+2]-pz;
        float h0=bb0+rx*w00+ry*w10+rz*w20;
        float h1=bb1+rx*w01+ry*w11+rz*w21;
        float h2=bb2+rx*w02+ry*w12+rz*w22;
        float r0=fmaxf(h0*sc0+sh0,0.f), r1=fmaxf(h1*sc1+sh1,0.f), r2=fmaxf(h2*sc2+sh2,0.f);
        float pr=r0*wa+r1*wb+r2*wc+bpc;
        float4 wA = *(const float4*)&wbuf[(size_t)g*8];
        float4 wB = *(const float4*)&wbuf[(size_t)g*8+4];
        float wm[8] = {wA.x,wA.y,wA.z,wA.w,wB.x,wB.y,wB.z,wB.w};
        float acc = bw2i;
        #pragma unroll
        for (int m=0;m<8;++m){
            float y3 = fmaxf(wm[m]*s3[m]+t3[m],0.f);
            acc += y3*w2col[m];
        }
        wf[t]=acc;
        comb[t]=xv[(size_t)jv*64+lane]+pr;
    }
    float mx = wf[0];
    #pragma unroll
    for (int t=1;t<16;++t) mx = fmaxf(mx, wf[t]);
    float ssum=0.f, osum=0.f;
    #pragma unroll
    for (int t=0;t<16;++t){ float e = __expf(wf[t]-mx); ssum += e; osum += e*comb[t]; }
    const float v = osum / ssum;
    if (f32) ((float*)out)[(size_t)n*64+lane] = v;
    else     ((bf16*)out)[(size_t)n*64+lane] = __float2bfloat16(v);
}

// ---------------------------------------------------------------- launcher
extern "C" void kernel_launch(void* const* d_in, const int* in_sizes, int n_in,
                              void* d_out, int out_size, void* d_ws, size_t ws_size,
                              hipStream_t stream)
{
    const void* p  = d_in[0];
    const void* x  = d_in[1];
    P20 prms;
    for (int i = 0; i < 20; ++i) prms.p[i] = d_in[3+i];

    // workspace layout (floats) — peak 12,019,056 floats = 48.08 MB (proven)
    float* W = (float*)d_ws;
    float* xqf    = W + 0;
    float* xkf    = W + 2097152;
    float* xvf    = W + 4194304;
    float* sqk    = W + 6291456;
    float* sqv    = W + 6324224;
    int*   idx_k  = (int*)(W + 6356992);
    int*   idx_v  = (int*)(W + 6881280);
    float* p32    = W + 7405568;   // 98304
    float* prm    = W + 7503872;   // 13490 (+pad)
    float* part1  = W + 7517376;   // 512*6 (slack)
    float* part2  = W + 7529664;   // 2048*128
    float* part3  = W + 7791808;   // 2048*16
    float* bn1aff = W + 7824576;   // 16
    float* bn2aff = W + 7824592;   // 128
    float* bn3aff = W + 7824720;   // 16
    int*   flags  = (int*)(W + 7824736); // 2 (+pad to 16)
    float* pdist  = W + 7824752;   // 32768*32 = 1,048,576 (dead after merges)
    int*   pidx   = (int*)(W + 8873328);  // 1,048,576 (dead after merges)
    float* wbuf   = W + 7824752;   // 4,194,304 — overlays pdist+pidx (written after merges)

    const float invP = 1.f / (float)NPAIR;

    k_sniff<<<1,256,0,stream>>>(x, d_in[3], flags);
    k_conv_prm<<<(NPRM+255)/256,256,0,stream>>>(prms, flags, prm);
    k_conv_p<<<(NPTS*3+255)/256,256,0,stream>>>(p, flags, p32);
    k_proj<<<2048,256,0,stream>>>(x, flags, prm, xqf,xkf,xvf, sqk,sqv);
    k_knn_part <<<1024,256,0,stream>>>(xkf, sqk, pdist, pidx);
    k_knn_merge<<<512,64,0,stream>>>(pdist, pidx, idx_k, p32, prm, part1, 1);
    k_knn_part <<<1024,256,0,stream>>>(xvf, sqv, pdist, pidx);
    k_knn_merge<<<512,64,0,stream>>>(pdist, pidx, idx_v, p32, prm, part1, 0);
    k_bnred<<<1,256,0,stream>>>(part1, 512, 3, prm+O_GP, prm+O_BTP, bn1aff, invP);
    k_rstats<<<2048,256,0,stream>>>(p32, xqf, xkf, idx_k, bn1aff, prm, part2);
    k_bnred<<<1,256,0,stream>>>(part2, 2048, 64, prm+O_G1, prm+O_BT1, bn2aff, invP);
    k_wstats<<<2048,256,0,stream>>>(p32, xqf, xkf, idx_k, bn1aff, prm, bn2aff, wbuf, part3);
    k_bnred<<<1,256,0,stream>>>(part3, 2048, 8, prm+O_G2, prm+O_BT2, bn3aff, invP);
    k_out<<<8192,256,0,stream>>>(p32, xvf, idx_k, idx_v, bn1aff, prm,
                                 wbuf, bn3aff, flags, d_out);
}

// Round 14
// 1194.843 us; speedup vs baseline: 1.6569x; 1.0680x over previous
//
#include <hip/hip_runtime.h>
#include <hip/hip_bf16.h>

typedef __hip_bfloat16 bf16;

#define NPTS  32768
#define NPB   4096
#define NPAIR (NPTS*16)
#define IMASK 32767
#define EPSB  1e-5f

// packed fp32 param-block offsets (floats)
#define O_WQ  0
#define O_BQ  4096
#define O_WK  4160
#define O_BK  8256
#define O_WV  8320
#define O_BV  12416
#define O_WP1 12480
#define O_BP1 12489
#define O_GP  12492
#define O_BTP 12495
#define O_WP2 12498
#define O_BP2 12690
#define O_G1  12754
#define O_BT1 12818
#define O_WW1 12882
#define O_BW1 13394
#define O_G2  13402
#define O_BT2 13410
#define O_WW2 13418
#define O_BW2 13482
#define NPRM  13490

__device__ __forceinline__ float b2f(bf16 v){ return __bfloat162float(v); }
__device__ __forceinline__ float u16f(unsigned short u){ return __uint_as_float(((unsigned)u)<<16); }
__device__ __forceinline__ float ldany(const void* p, long long i, int f32){
    return f32 ? ((const float*)p)[i] : b2f(((const bf16*)p)[i]);
}

// ---------------------------------------------------------------- dtype sniff
__global__ __launch_bounds__(256) void k_sniff(const void* x, const void* wq, int* flags)
{
    __shared__ float red[2][4];
    const unsigned short* xu = (const unsigned short*)x;
    const unsigned short* wu = (const unsigned short*)wq;
    const int tid = threadIdx.x, lane = tid & 63, wvi = tid >> 6;
    float mx = fabsf(u16f(xu[tid]));
    float mw = fabsf(u16f(wu[tid]));
    for (int off = 32; off; off >>= 1){
        mx = fmaxf(mx, __shfl_down(mx, off));
        mw = fmaxf(mw, __shfl_down(mw, off));
    }
    if (lane == 0){ red[0][wvi] = mx; red[1][wvi] = mw; }
    __syncthreads();
    if (tid == 0){
        float ax = fmaxf(fmaxf(red[0][0], red[0][1]), fmaxf(red[0][2], red[0][3]));
        float aw = fmaxf(fmaxf(red[1][0], red[1][1]), fmaxf(red[1][2], red[1][3]));
        flags[0] = (ax > 1e6f) ? 1 : 0;   // p/x family is fp32
        flags[1] = (aw > 1e6f) ? 1 : 0;   // weight family is fp32
    }
}

// ---------------------------------------------------------------- param canonicalization -> fp32 block
struct P20 { const void* p[20]; };

__global__ __launch_bounds__(256) void k_conv_prm(P20 t, const int* __restrict__ flags,
                                                  float* __restrict__ prm)
{
    const int i = blockIdx.x*256 + threadIdx.x;
    if (i >= NPRM) return;
    const int f = flags[1];
    const int sz[20] = {4096,64,4096,64,4096,64,9,3,3,3,192,64,64,64,512,8,8,8,64,8};
    int seg = 0, rem = i;
    while (rem >= sz[seg]){ rem -= sz[seg]; ++seg; }
    prm[i] = ldany(t.p[seg], rem, f);
}

__global__ __launch_bounds__(256) void k_conv_p(const void* __restrict__ p,
                                                const int* __restrict__ flags,
                                                float* __restrict__ p32)
{
    const int i = blockIdx.x*256 + threadIdx.x;
    if (i < NPTS*3) p32[i] = ldany(p, i, flags[0]);
}

// ---------------------------------------------------------------- projections (16 pts/block)
__global__ __launch_bounds__(256) void k_proj(
    const void* __restrict__ x, const int* __restrict__ flags,
    const float* __restrict__ prm,
    float* __restrict__ xq, float* __restrict__ xk, float* __restrict__ xv,
    float* __restrict__ sqk, float* __restrict__ sqv)
{
    __shared__ float WQ[4096], WK[4096], WV[4096], BQ[64], BK[64], BV[64];
    const int tid = threadIdx.x;
    for (int i = tid; i < 4096; i += 256){
        WQ[i] = prm[O_WQ+i]; WK[i] = prm[O_WK+i]; WV[i] = prm[O_WV+i];
    }
    if (tid < 64){ BQ[tid]=prm[O_BQ+tid]; BK[tid]=prm[O_BK+tid]; BV[tid]=prm[O_BV+tid]; }
    const int f32 = flags[0];
    __syncthreads();
    const int lane = tid & 63, wvi = tid >> 6;
    const int ptbase = blockIdx.x*16 + wvi*4;
    for (int it = 0; it < 4; ++it){
        const int pt = ptbase + it;
        float xl = ldany(x, (long long)pt*64 + lane, f32);
        float aq = BQ[lane], ak = BK[lane], av = BV[lane];
        #pragma unroll
        for (int k = 0; k < 64; ++k){
            float xb = __shfl(xl, k);
            aq += xb*WQ[k*64+lane];
            ak += xb*WK[k*64+lane];
            av += xb*WV[k*64+lane];
        }
        xq[pt*64+lane]=aq; xk[pt*64+lane]=ak; xv[pt*64+lane]=av;
        float s1 = ak*ak, s2 = av*av;
        for (int off=32; off; off>>=1){ s1 += __shfl_down(s1,off); s2 += __shfl_down(s2,off); }
        if (lane==0){ sqk[pt]=s1; sqv[pt]=s2; }
    }
}

// ---------------------------------------------------------------- KNN partial (both KNNs in ONE dispatch)
// grid 2048: kid = bid>>10 (0: k-features, 1: v-features); within kid:
// b = bid>>7 & 7, qt = (bid>>1)&63, cs = bid&1. Block: 64 queries vs 2048 cands (32 chunks of 64).
// Tile 4q x 4c; register top-16 in owner lanes; cooperative 4-lane mask filter. (round-8 proven core)
__global__ __launch_bounds__(256) void k_knn_part(
    const float* __restrict__ featk, const float* __restrict__ featv,
    const float* __restrict__ sqk, const float* __restrict__ sqv,
    float* __restrict__ pdist, int* __restrict__ pidx)
{
    __shared__ __attribute__((aligned(16))) float Qf[64*68];
    __shared__ __attribute__((aligned(16))) float Cf[64*68];  // cand tile; reused as dist tile [64][68]
    __shared__ float sqC[64];
    const int tid = threadIdx.x;
    const int kid = blockIdx.x >> 10;
    const int bid = blockIdx.x & 1023;
    const float* feat = kid ? featv : featk;
    const float* sq   = kid ? sqv  : sqk;
    const int b  = bid >> 7;
    const int qt = (bid >> 1) & 63;
    const int cs = bid & 1;
    const int q0 = b*NPB + qt*64;
    const int c00 = b*NPB + cs*2048;
    for (int f = tid; f < 64*16; f += 256){
        int r = f >> 4, c4 = f & 15;
        *(float4*)&Qf[r*68 + 4*c4] = *(const float4*)&feat[(size_t)(q0+r)*64 + 4*c4];
    }
    float dl[16]; int il[16];
    #pragma unroll
    for (int i=0;i<16;++i){ dl[i] = 3.4e38f; il[i] = 0; }
    const int lane = tid & 63, wv = tid >> 6;
    const int qsub = tid & 15, csub = tid >> 4;       // compute-phase mapping
    const int selq = (wv << 4) + (lane >> 2);         // selection row (0..63)
    const int sub  = lane & 3;
    const int owner = lane & ~3;
    __syncthreads();
    for (int chn = 0; chn < 32; ++chn){
        const int c0 = c00 + chn*64;
        for (int f = tid; f < 64*16; f += 256){
            int r = f >> 4, c4 = f & 15;
            *(float4*)&Cf[r*68 + 4*c4] = *(const float4*)&feat[(size_t)(c0+r)*64 + 4*c4];
        }
        if (tid < 64) sqC[tid] = sq[c0 + tid];
        __syncthreads();
        float acc[4][4];
        #pragma unroll
        for (int a=0;a<4;++a)
            #pragma unroll
            for (int e=0;e<4;++e) acc[a][e]=0.f;
        #pragma unroll 4
        for (int k4 = 0; k4 < 16; ++k4){
            float4 qv[4], cv[4];
            #pragma unroll
            for (int a=0;a<4;++a) qv[a] = *(const float4*)&Qf[(qsub+16*a)*68 + 4*k4];
            #pragma unroll
            for (int e=0;e<4;++e) cv[e] = *(const float4*)&Cf[(csub+16*e)*68 + 4*k4];
            #pragma unroll
            for (int a=0;a<4;++a)
                #pragma unroll
                for (int e=0;e<4;++e){
                    acc[a][e] += qv[a].x*cv[e].x;
                    acc[a][e] += qv[a].y*cv[e].y;
                    acc[a][e] += qv[a].z*cv[e].z;
                    acc[a][e] += qv[a].w*cv[e].w;
                }
        }
        __syncthreads();
        #pragma unroll
        for (int a=0;a<4;++a)
            #pragma unroll
            for (int e=0;e<4;++e){
                int qq = qsub+16*a, cc = csub+16*e;
                Cf[qq*68 + cc] = sqC[cc] - 2.f*acc[a][e];
            }
        __syncthreads();
        // ---- cooperative selection: 4 lanes per query build hit-mask
        float worst = __shfl(dl[15], owner);
        unsigned m16 = 0;
        const int rowoff = selq*68 + sub*16;
        #pragma unroll
        for (int r = 0; r < 4; ++r){
            float4 v = *(const float4*)&Cf[rowoff + 4*r];
            m16 |= (v.x < worst ? 1u : 0u) << (4*r+0);
            m16 |= (v.y < worst ? 1u : 0u) << (4*r+1);
            m16 |= (v.z < worst ? 1u : 0u) << (4*r+2);
            m16 |= (v.w < worst ? 1u : 0u) << (4*r+3);
        }
        unsigned ma = __shfl(m16, owner+0), mb = __shfl(m16, owner+1);
        unsigned mc = __shfl(m16, owner+2), md = __shfl(m16, owner+3);
        if (sub == 0){
            unsigned long long m = (unsigned long long)ma
                                 | ((unsigned long long)mb << 16)
                                 | ((unsigned long long)mc << 32)
                                 | ((unsigned long long)md << 48);
            const int qrow = selq*68;
            while (m){
                int c = (int)__builtin_ctzll(m); m &= m - 1;
                float d = Cf[qrow + c];
                if (d < dl[15]){
                    int gi = c0 + c;
                    #pragma unroll
                    for (int i = 15; i >= 1; --i){
                        bool sh   = dl[i-1] > d;
                        bool here = !sh && (dl[i] > d);
                        dl[i] = sh ? dl[i-1] : (here ? d  : dl[i]);
                        il[i] = sh ? il[i-1] : (here ? gi : il[i]);
                    }
                    bool h0 = dl[0] > d;
                    dl[0] = h0 ? d  : dl[0];
                    il[0] = h0 ? gi : il[0];
                }
            }
        }
        __syncthreads();
    }
    if (sub == 0){
        const size_t base = ((size_t)(q0+selq)*4 + kid*2 + cs)*16;
        #pragma unroll
        for (int i=0;i<16;++i){ pdist[base+i] = dl[i]; pidx[base+i] = il[i]; }
    }
}

// ---------------------------------------------------------------- KNN merge (both KNNs in ONE dispatch)
// grid 1024: kid = bid>>9 (0 -> idx_k + BN1 stats, 1 -> idx_v). Stable lexicographic merge.
__global__ __launch_bounds__(64) void k_knn_merge(
    const float* __restrict__ pdist, const int* __restrict__ pidx,
    int* __restrict__ idx_k, int* __restrict__ idx_v,
    const float* __restrict__ p32, const float* __restrict__ prm,
    float* __restrict__ part1)
{
    __shared__ float D[64][33];
    __shared__ int   I[64][33];
    const int tid = threadIdx.x;
    const int kid = blockIdx.x >> 9;
    const int blk = blockIdx.x & 511;
    const size_t gq = (size_t)blk*64 + tid;
    const size_t src = gq*64 + (size_t)kid*32;
    #pragma unroll
    for (int j4 = 0; j4 < 8; ++j4){
        float4 dv = *(const float4*)&pdist[src + 4*j4];
        int4   iv = *(const int4*)  &pidx [src + 4*j4];
        D[tid][4*j4+0]=dv.x; D[tid][4*j4+1]=dv.y; D[tid][4*j4+2]=dv.z; D[tid][4*j4+3]=dv.w;
        I[tid][4*j4+0]=iv.x; I[tid][4*j4+1]=iv.y; I[tid][4*j4+2]=iv.z; I[tid][4*j4+3]=iv.w;
    }
    int mi[16];
    int p0 = 0, p1 = 16;
    #pragma unroll
    for (int o = 0; o < 16; ++o){
        float d0 = D[tid][p0], d1 = D[tid][p1];
        int   i0 = I[tid][p0], i1 = I[tid][p1];
        bool take1 = (d1 < d0) || (d1 == d0 && i1 < i0);
        mi[o] = take1 ? i1 : i0;
        if (take1) ++p1; else ++p0;
    }
    int* idx_out = kid ? idx_v : idx_k;
    #pragma unroll
    for (int o4 = 0; o4 < 4; ++o4)
        *(int4*)&idx_out[gq*16 + 4*o4] = make_int4(mi[4*o4], mi[4*o4+1], mi[4*o4+2], mi[4*o4+3]);
    if (kid) return;
    // BN1 stats: h = p_rel @ wp1 + bp1 over this query's 16 k-neighbors
    const float w00=prm[O_WP1+0], w01=prm[O_WP1+1], w02=prm[O_WP1+2];
    const float w10=prm[O_WP1+3], w11=prm[O_WP1+4], w12=prm[O_WP1+5];
    const float w20=prm[O_WP1+6], w21=prm[O_WP1+7], w22=prm[O_WP1+8];
    const float bb0=prm[O_BP1+0], bb1=prm[O_BP1+1], bb2=prm[O_BP1+2];
    const float px=p32[gq*3+0], py=p32[gq*3+1], pz=p32[gq*3+2];
    float s0=0.f,s1=0.f,s2=0.f,t0=0.f,t1=0.f,t2=0.f;
    #pragma unroll
    for (int o = 0; o < 16; ++o){
        const int j = mi[o] & IMASK;
        float rx = p32[j*3+0]-px, ry = p32[j*3+1]-py, rz = p32[j*3+2]-pz;
        float h0 = bb0 + rx*w00 + ry*w10 + rz*w20;
        float h1 = bb1 + rx*w01 + ry*w11 + rz*w21;
        float h2 = bb2 + rx*w02 + ry*w12 + rz*w22;
        s0+=h0; s1+=h1; s2+=h2; t0+=h0*h0; t1+=h1*h1; t2+=h2*h2;
    }
    for (int off=32; off; off>>=1){
        s0+=__shfl_down(s0,off); s1+=__shfl_down(s1,off); s2+=__shfl_down(s2,off);
        t0+=__shfl_down(t0,off); t1+=__shfl_down(t1,off); t2+=__shfl_down(t2,off);
    }
    if (tid == 0){
        float* pp = part1 + blk*6;
        pp[0]=s0; pp[1]=s1; pp[2]=s2; pp[3]=t0; pp[4]=t1; pp[5]=t2;
    }
}

// ---------------------------------------------------------------- BN partial reduce -> affine
__global__ __launch_bounds__(256) void k_bnred(
    const float* __restrict__ part, int G, int C,
    const float* __restrict__ gamma, const float* __restrict__ beta,
    float* __restrict__ aff, float invCount)
{
    __shared__ float tot[128];
    const int tid = threadIdx.x, lane = tid & 63, wvi = tid >> 6;
    const int S = 2*C;
    for (int s = wvi; s < S; s += 4){
        float v = 0.f;
        for (int idx = lane; idx < G; idx += 64) v += part[(size_t)idx*S + s];
        for (int off=32; off; off>>=1) v += __shfl_down(v, off);
        if (lane == 0) tot[s] = v;
    }
    __syncthreads();
    if (tid < C){
        float mean = tot[tid]*invCount;
        float var  = fmaxf(tot[C+tid]*invCount - mean*mean, 0.f);
        float sc = gamma[tid] * rsqrtf(var + EPSB);
        aff[tid]   = sc;
        aff[C+tid] = beta[tid] - mean*sc;
    }
}

// ---------------------------------------------------------------- BN2 stats over r (unrolled x4)
__global__ __launch_bounds__(256) void k_rstats(
    const float* __restrict__ p32,
    const float* __restrict__ xq, const float* __restrict__ xk, const int* __restrict__ idx_k,
    const float* __restrict__ bn1aff, const float* __restrict__ prm,
    float* __restrict__ part2)
{
    const int tid = threadIdx.x, lane = tid & 63, wvi = tid >> 6;
    const float wa = prm[O_WP2+lane], wb = prm[O_WP2+64+lane], wc = prm[O_WP2+128+lane];
    const float bpc = prm[O_BP2+lane];
    const float w00=prm[O_WP1+0], w01=prm[O_WP1+1], w02=prm[O_WP1+2];
    const float w10=prm[O_WP1+3], w11=prm[O_WP1+4], w12=prm[O_WP1+5];
    const float w20=prm[O_WP1+6], w21=prm[O_WP1+7], w22=prm[O_WP1+8];
    const float bb0=prm[O_BP1+0], bb1=prm[O_BP1+1], bb2=prm[O_BP1+2];
    const float sc0=bn1aff[0], sc1=bn1aff[1], sc2=bn1aff[2];
    const float sh0=bn1aff[3], sh1=bn1aff[4], sh2=bn1aff[5];
    const int base = (blockIdx.x*4 + wvi) * 64;
    float asum=0.f, asq=0.f;
    float px=0.f, py=0.f, pz=0.f, xql=0.f;
    for (int e4 = 0; e4 < 16; ++e4){
        const int gb = base + e4*4;
        if ((gb & 15) == 0){
            const int n = gb >> 4;
            px=p32[n*3+0]; py=p32[n*3+1]; pz=p32[n*3+2];
            xql = xq[(size_t)n*64+lane];
        }
        int4 jj = *(const int4*)&idx_k[gb];
        int j[4] = { jj.x & IMASK, jj.y & IMASK, jj.z & IMASK, jj.w & IMASK };
        float kx[4], qx[4][3];
        #pragma unroll
        for (int u=0;u<4;++u){
            qx[u][0]=p32[j[u]*3+0]; qx[u][1]=p32[j[u]*3+1]; qx[u][2]=p32[j[u]*3+2];
            kx[u] = xk[(size_t)j[u]*64+lane];
        }
        #pragma unroll
        for (int u=0;u<4;++u){
            float rx = qx[u][0]-px, ry = qx[u][1]-py, rz = qx[u][2]-pz;
            float h0 = bb0 + rx*w00 + ry*w10 + rz*w20;
            float h1 = bb1 + rx*w01 + ry*w11 + rz*w21;
            float h2 = bb2 + rx*w02 + ry*w12 + rz*w22;
            float r0 = fmaxf(h0*sc0+sh0, 0.f), r1 = fmaxf(h1*sc1+sh1,0.f), r2 = fmaxf(h2*sc2+sh2,0.f);
            float pr = r0*wa + r1*wb + r2*wc + bpc;
            float rv = kx[u] - xql + pr;
            asum += rv; asq += rv*rv;
        }
    }
    __shared__ float red[4][128];
    red[wvi][lane] = asum; red[wvi][64+lane] = asq;
    __syncthreads();
    if (tid < 128) part2[(size_t)blockIdx.x*128 + tid] = red[0][tid]+red[1][tid]+red[2][tid]+red[3][tid];
}

// ---------------------------------------------------------------- BN3 stats over w (+ wbuf store)
__global__ __launch_bounds__(256) void k_wstats(
    const float* __restrict__ p32,
    const float* __restrict__ xq, const float* __restrict__ xk, const int* __restrict__ idx_k,
    const float* __restrict__ bn1aff, const float* __restrict__ prm,
    const float* __restrict__ bn2aff, float* __restrict__ wbuf, float* __restrict__ part3)
{
    __shared__ float4 PRW[64];
    __shared__ float2 SS2[64];
    __shared__ float4 W1A[64], W1B[64];
    const int tid = threadIdx.x;
    if (tid < 64){
        PRW[tid] = make_float4(prm[O_WP2+tid], prm[O_WP2+64+tid], prm[O_WP2+128+tid], prm[O_BP2+tid]);
        SS2[tid] = make_float2(bn2aff[tid], bn2aff[64+tid]);
        W1A[tid] = make_float4(prm[O_WW1+tid*8+0],prm[O_WW1+tid*8+1],prm[O_WW1+tid*8+2],prm[O_WW1+tid*8+3]);
        W1B[tid] = make_float4(prm[O_WW1+tid*8+4],prm[O_WW1+tid*8+5],prm[O_WW1+tid*8+6],prm[O_WW1+tid*8+7]);
    }
    __syncthreads();
    const int g = blockIdx.x*256 + tid;
    const int n = g >> 4;
    const int j = idx_k[g] & IMASK;
    const float w00=prm[O_WP1+0], w01=prm[O_WP1+1], w02=prm[O_WP1+2];
    const float w10=prm[O_WP1+3], w11=prm[O_WP1+4], w12=prm[O_WP1+5];
    const float w20=prm[O_WP1+6], w21=prm[O_WP1+7], w22=prm[O_WP1+8];
    const float bb0=prm[O_BP1+0], bb1=prm[O_BP1+1], bb2=prm[O_BP1+2];
    const float sc0=bn1aff[0], sc1=bn1aff[1], sc2=bn1aff[2];
    const float sh0=bn1aff[3], sh1=bn1aff[4], sh2=bn1aff[5];
    float rx = p32[j*3+0] - p32[n*3+0];
    float ry = p32[j*3+1] - p32[n*3+1];
    float rz = p32[j*3+2] - p32[n*3+2];
    float h0 = bb0 + rx*w00 + ry*w10 + rz*w20;
    float h1 = bb1 + rx*w01 + ry*w11 + rz*w21;
    float h2 = bb2 + rx*w02 + ry*w12 + rz*w22;
    float r0 = fmaxf(h0*sc0+sh0, 0.f), r1 = fmaxf(h1*sc1+sh1,0.f), r2 = fmaxf(h2*sc2+sh2,0.f);
    float wacc[8];
    #pragma unroll
    for (int i=0;i<8;++i) wacc[i] = prm[O_BW1+i];
    const float4* kr = (const float4*)(xk + (size_t)j*64);
    const float4* qr = (const float4*)(xq + (size_t)n*64);
    #pragma unroll
    for (int c4=0;c4<16;++c4){
        float4 kv = kr[c4], qv = qr[c4];
        float kvv[4] = {kv.x,kv.y,kv.z,kv.w};
        float qvv[4] = {qv.x,qv.y,qv.z,qv.w};
        #pragma unroll
        for (int d=0; d<4; ++d){
            int c = 4*c4 + d;
            float4 pw = PRW[c]; float2 ss = SS2[c];
            float pr = r0*pw.x + r1*pw.y + r2*pw.z + pw.w;
            float rr = kvv[d] - qvv[d] + pr;
            float y = fmaxf(rr*ss.x + ss.y, 0.f);
            float4 wA = W1A[c], wB = W1B[c];
            wacc[0]+=y*wA.x; wacc[1]+=y*wA.y; wacc[2]+=y*wA.z; wacc[3]+=y*wA.w;
            wacc[4]+=y*wB.x; wacc[5]+=y*wB.y; wacc[6]+=y*wB.z; wacc[7]+=y*wB.w;
        }
    }
    *(float4*)&wbuf[(size_t)g*8]   = make_float4(wacc[0],wacc[1],wacc[2],wacc[3]);
    *(float4*)&wbuf[(size_t)g*8+4] = make_float4(wacc[4],wacc[5],wacc[6],wacc[7]);
    float st[16];
    #pragma unroll
    for (int i=0;i<8;++i){ st[i]=wacc[i]; st[8+i]=wacc[i]*wacc[i]; }
    for (int off=32; off; off>>=1){
        #pragma unroll
        for (int k=0;k<16;++k) st[k] += __shfl_down(st[k], off);
    }
    __shared__ float red[4][16];
    const int lane = tid&63, wvi = tid>>6;
    if (lane==0){
        #pragma unroll
        for (int k=0;k<16;++k) red[wvi][k]=st[k];
    }
    __syncthreads();
    if (tid < 16) part3[(size_t)blockIdx.x*16 + tid] = red[0][tid]+red[1][tid]+red[2][tid]+red[3][tid];
}

// ---------------------------------------------------------------- final (reads wbuf; no shfl chain)
__global__ __launch_bounds__(256) void k_out(
    const float* __restrict__ p32, const float* __restrict__ xv,
    const int* __restrict__ idx_k, const int* __restrict__ idx_v,
    const float* __restrict__ bn1aff, const float* __restrict__ prm,
    const float* __restrict__ wbuf, const float* __restrict__ bn3aff,
    const int* __restrict__ flags, void* __restrict__ out)
{
    const int tid = threadIdx.x, lane = tid & 63, wvi = tid >> 6;
    const int n = blockIdx.x*4 + wvi;
    const int f32 = flags[0];
    const float w00=prm[O_WP1+0], w01=prm[O_WP1+1], w02=prm[O_WP1+2];
    const float w10=prm[O_WP1+3], w11=prm[O_WP1+4], w12=prm[O_WP1+5];
    const float w20=prm[O_WP1+6], w21=prm[O_WP1+7], w22=prm[O_WP1+8];
    const float bb0=prm[O_BP1+0], bb1=prm[O_BP1+1], bb2=prm[O_BP1+2];
    const float sc0=bn1aff[0], sc1=bn1aff[1], sc2=bn1aff[2];
    const float sh0=bn1aff[3], sh1=bn1aff[4], sh2=bn1aff[5];
    const float wa=prm[O_WP2+lane], wb=prm[O_WP2+64+lane], wc=prm[O_WP2+128+lane];
    const float bpc=prm[O_BP2+lane];
    const int i = lane & 7;
    float s3[8], t3[8], w2col[8];
    #pragma unroll
    for (int m=0;m<8;++m){
        s3[m]=bn3aff[m]; t3[m]=bn3aff[8+m];
        w2col[m]=prm[O_WW2+m*8+i];
    }
    const float bw2i = prm[O_BW2+i];
    const float px=p32[n*3+0], py=p32[n*3+1], pz=p32[n*3+2];
    float comb[16], wf[16];
    #pragma unroll
    for (int t=0;t<16;++t){
        const int g = n*16 + t;
        const int jk = idx_k[g] & IMASK;
        const int jv = idx_v[g] & IMASK;
        float rx=p32[jk*3+0]-px, ry=p32[jk*3+1]-py, rz=p32[jk*3+2]-pz;
        float h0=bb0+rx*w00+ry*w10+rz*w20;
        float h1=bb1+rx*w01+ry*w11+rz*w21;
        float h2=bb2+rx*w02+ry*w12+rz*w22;
        float r0=fmaxf(h0*sc0+sh0,0.f), r1=fmaxf(h1*sc1+sh1,0.f), r2=fmaxf(h2*sc2+sh2,0.f);
        float pr=r0*wa+r1*wb+r2*wc+bpc;
        float4 wA = *(const float4*)&wbuf[(size_t)g*8];
        float4 wB = *(const float4*)&wbuf[(size_t)g*8+4];
        float wm[8] = {wA.x,wA.y,wA.z,wA.w,wB.x,wB.y,wB.z,wB.w};
        float acc = bw2i;
        #pragma unroll
        for (int m=0;m<8;++m){
            float y3 = fmaxf(wm[m]*s3[m]+t3[m],0.f);
            acc += y3*w2col[m];
        }
        wf[t]=acc;
        comb[t]=xv[(size_t)jv*64+lane]+pr;
    }
    float mx = wf[0];
    #pragma unroll
    for (int t=1;t<16;++t) mx = fmaxf(mx, wf[t]);
    float ssum=0.f, osum=0.f;
    #pragma unroll
    for (int t=0;t<16;++t){ float e = __expf(wf[t]-mx); ssum += e; osum += e*comb[t]; }
    const float v = osum / ssum;
    if (f32) ((float*)out)[(size_t)n*64+lane] = v;
    else     ((bf16*)out)[(size_t)n*64+lane] = __float2bfloat16(v);
}

// ---------------------------------------------------------------- launcher
extern "C" void kernel_launch(void* const* d_in, const int* in_sizes, int n_in,
                              void* d_out, int out_size, void* d_ws, size_t ws_size,
                              hipStream_t stream)
{
    const void* p  = d_in[0];
    const void* x  = d_in[1];
    P20 prms;
    for (int i = 0; i < 20; ++i) prms.p[i] = d_in[3+i];

    // workspace layout (floats) — peak 12,019,056 floats = 48.08 MB (round-4 proven footprint)
    float* W = (float*)d_ws;
    float* xqf    = W + 0;
    float* xkf    = W + 2097152;
    float* xvf    = W + 4194304;
    float* sqk    = W + 6291456;
    float* sqv    = W + 6324224;
    int*   idx_k  = (int*)(W + 6356992);
    int*   idx_v  = (int*)(W + 6881280);
    float* p32    = W + 7405568;   // 98304
    float* prm    = W + 7503872;   // 13490 (+pad)
    float* part1  = W + 7517376;   // 512*6 (slack)
    float* part2  = W + 7529664;   // 2048*128
    float* part3  = W + 7791808;   // 2048*16
    float* bn1aff = W + 7824576;   // 16
    float* bn2aff = W + 7824592;   // 128
    float* bn3aff = W + 7824720;   // 16
    int*   flags  = (int*)(W + 7824736); // 2 (+pad to 16)
    float* pdist  = W + 7824752;   // 32768*64 = 2,097,152 (dead after merge)
    int*   pidx   = (int*)(W + 9921904);  // 2,097,152 (dead after merge)
    float* wbuf   = W + 7824752;   // 4,194,304 — overlays pdist+pidx (written after merge)

    const float invP = 1.f / (float)NPAIR;

    k_sniff<<<1,256,0,stream>>>(x, d_in[3], flags);
    k_conv_prm<<<(NPRM+255)/256,256,0,stream>>>(prms, flags, prm);
    k_conv_p<<<(NPTS*3+255)/256,256,0,stream>>>(p, flags, p32);
    k_proj<<<2048,256,0,stream>>>(x, flags, prm, xqf,xkf,xvf, sqk,sqv);
    k_knn_part <<<2048,256,0,stream>>>(xkf, xvf, sqk, sqv, pdist, pidx);
    k_knn_merge<<<1024,64,0,stream>>>(pdist, pidx, idx_k, idx_v, p32, prm, part1);
    k_bnred<<<1,256,0,stream>>>(part1, 512, 3, prm+O_GP, prm+O_BTP, bn1aff, invP);
    k_rstats<<<2048,256,0,stream>>>(p32, xqf, xkf, idx_k, bn1aff, prm, part2);
    k_bnred<<<1,256,0,stream>>>(part2, 2048, 64, prm+O_G1, prm+O_BT1, bn2aff, invP);
    k_wstats<<<2048,256,0,stream>>>(p32, xqf, xkf, idx_k, bn1aff, prm, bn2aff, wbuf, part3);
    k_bnred<<<1,256,0,stream>>>(part3, 2048, 8, prm+O_G2, prm+O_BT2, bn3aff, invP);
    k_out<<<8192,256,0,stream>>>(p32, xvf, idx_k, idx_v, bn1aff, prm,
                                 wbuf, bn3aff, flags, d_out);
}